// Round 3
// baseline (209.751 us; speedup 1.0000x reference)
//
#include <hip/hip_runtime.h>

// B=2, S=2048, E=1024, H=16, D=64.  M = B*S = 4096.
// Pipeline: prep (f32->bf16 + weight transposes) -> GEMM1 (QKV, writes q/k [bh][s][d],
// v transposed [bh][d][s]) -> flash attention (writes o [m][1024] bf16) -> GEMM3 (f32 out).

typedef __attribute__((ext_vector_type(8))) __bf16 bf16x8;
typedef __attribute__((ext_vector_type(4))) __bf16 bf16x4;
typedef __attribute__((ext_vector_type(4))) float  f32x4;

#define LOG2E 1.4426950408889634f
#define SM_SC (0.125f * LOG2E)   // softmax scale folded with log2(e)

static __device__ __forceinline__ void gl2lds16(const void* g, void* l) {
    __builtin_amdgcn_global_load_lds(
        (__attribute__((address_space(1))) void*)(void*)g,
        (__attribute__((address_space(3))) void*)l, 16, 0, 0);
}

// ---------------- prep kernels ----------------
__global__ void prep_x_kern(const float* __restrict__ x, __bf16* __restrict__ xb) {
    int i = (blockIdx.x * 256 + threadIdx.x) * 4;
    f32x4 v = *(const f32x4*)(x + i);
    bf16x4 o = { (__bf16)v[0], (__bf16)v[1], (__bf16)v[2], (__bf16)v[3] };
    *(bf16x4*)(xb + i) = o;
}

// wt[n][k] = W_p[h][k][d],  n = p*1024 + h*64 + d (p in {q,k,v}); bias[n] = b_p[h*64+d]
__global__ void prep_wqkv_kern(const float* __restrict__ Wq, const float* __restrict__ Wk,
                               const float* __restrict__ Wv, const float* __restrict__ bq,
                               const float* __restrict__ bk, const float* __restrict__ bv,
                               __bf16* __restrict__ wt, float* __restrict__ bias) {
    int idx = blockIdx.x * 256 + threadIdx.x;     // 0..3145727
    int n = idx >> 10, kk = idx & 1023;
    int p = n >> 10, rm = n & 1023;
    int h = rm >> 6, d = rm & 63;
    const float* W = (p == 0) ? Wq : (p == 1) ? Wk : Wv;
    wt[idx] = (__bf16)W[(h << 16) + (kk << 6) + d];
    if (idx < 3072) {
        int p2 = idx >> 10, rm2 = idx & 1023;
        const float* bb = (p2 == 0) ? bq : (p2 == 1) ? bk : bv;
        bias[idx] = bb[rm2];
    }
}

// wt[n][k] = W_o[k][n]
__global__ void prep_wo_kern(const float* __restrict__ Wo, __bf16* __restrict__ wt) {
    int idx = blockIdx.x * 256 + threadIdx.x;    // 0..1048575
    int n = idx >> 10, kk = idx & 1023;
    wt[idx] = (__bf16)Wo[(kk << 10) + n];
}

// ---------------- GEMM: C[M][N] = A[M][1024] * Bt[N][1024]^T (+bias) ----------------
// 128x128 tile, BK=64, 4 waves each computing 64x64 via 4x4 of 16x16x32 MFMA.
// EPI=0: scatter bf16 into q/k ([bh][s][d]) and vT ([bh][d][s]) per n = p*1024+h*64+d
// EPI=1: f32 out + bias
template <int EPI>
__global__ void __launch_bounds__(256, 2)
gemm_bt(const __bf16* __restrict__ A, const __bf16* __restrict__ Bt,
        const float* __restrict__ bias,
        __bf16* __restrict__ outq, __bf16* __restrict__ outk, __bf16* __restrict__ outv,
        float* __restrict__ outf)
{
    __shared__ __align__(16) __bf16 As[128 * 64];
    __shared__ __align__(16) __bf16 Bs[128 * 64];
    const int tid = threadIdx.x;
    const int wid = tid >> 6, lane = tid & 63;
    const int r = lane & 15, g = lane >> 4;
    const int m0 = blockIdx.y << 7, n0 = blockIdx.x << 7;
    const int wr = wid >> 1, wc = wid & 1;
    f32x4 acc[4][4] = {};
    for (int k0 = 0; k0 < 1024; k0 += 64) {
        #pragma unroll
        for (int c = 0; c < 4; ++c) {
            int cq = (c * 4 + wid) * 64 + lane;   // 16B chunk index in [0,1024)
            int row = cq >> 3, ci = cq & 7;
            gl2lds16(A  + (((size_t)(m0 + row)) << 10) + k0 + ci * 8, As + (c * 4 + wid) * 512);
            gl2lds16(Bt + (((size_t)(n0 + row)) << 10) + k0 + ci * 8, Bs + (c * 4 + wid) * 512);
        }
        __syncthreads();
        bf16x8 af[2][4], bfr[2][4];
        #pragma unroll
        for (int kh = 0; kh < 2; ++kh)
            #pragma unroll
            for (int i = 0; i < 4; ++i) {
                af[kh][i]  = *(const bf16x8*)&As[(wr * 64 + i * 16 + r) * 64 + kh * 32 + g * 8];
                bfr[kh][i] = *(const bf16x8*)&Bs[(wc * 64 + i * 16 + r) * 64 + kh * 32 + g * 8];
            }
        #pragma unroll
        for (int kh = 0; kh < 2; ++kh)
            #pragma unroll
            for (int mi = 0; mi < 4; ++mi)
                #pragma unroll
                for (int ni = 0; ni < 4; ++ni)
                    acc[mi][ni] = __builtin_amdgcn_mfma_f32_16x16x32_bf16(
                        af[kh][mi], bfr[kh][ni], acc[mi][ni], 0, 0, 0);
        __syncthreads();
    }
    if (EPI == 0) {
        #pragma unroll
        for (int ni = 0; ni < 4; ++ni) {
            int n = n0 + wc * 64 + ni * 16 + r;
            float bv = bias[n];
            int p = n >> 10, rem = n & 1023, h = rem >> 6, d = rem & 63;
            #pragma unroll
            for (int mi = 0; mi < 4; ++mi) {
                int mb = m0 + wr * 64 + mi * 16 + g * 4;
                int b = mb >> 11, s = mb & 2047;
                f32x4 v = acc[mi][ni];
                if (p < 2) {
                    __bf16* dst = (p == 0) ? outq : outk;
                    size_t base = (((size_t)(b * 16 + h)) * 2048 + s) * 64 + d;
                    #pragma unroll
                    for (int j = 0; j < 4; ++j)
                        dst[base + (size_t)j * 64] = (__bf16)(v[j] + bv);
                } else {
                    bf16x4 pk = { (__bf16)(v[0] + bv), (__bf16)(v[1] + bv),
                                  (__bf16)(v[2] + bv), (__bf16)(v[3] + bv) };
                    *(bf16x4*)&outv[(((size_t)(b * 16 + h)) * 64 + d) * 2048 + s] = pk;
                }
            }
        }
    } else {
        #pragma unroll
        for (int ni = 0; ni < 4; ++ni) {
            int n = n0 + wc * 64 + ni * 16 + r;
            float bv = bias[n];
            #pragma unroll
            for (int mi = 0; mi < 4; ++mi) {
                int mb = m0 + wr * 64 + mi * 16 + g * 4;
                f32x4 v = acc[mi][ni];
                #pragma unroll
                for (int j = 0; j < 4; ++j)
                    outf[((size_t)(mb + j) << 10) + n] = v[j] + bv;
            }
        }
    }
}

// ---------------- flash attention ----------------
// grid (32, 32): x = 64-row Q-block (reversed for LPT), y = b*16+h -> 1024 blocks,
// 4 blocks/CU resident. 4 waves x 16 q-rows. K tile [64][64], V^T tile [64][64] in
// padded LDS. Register async-stage: next tile's K/V loads issued before compute,
// LDS writes after the barrier.
__global__ void __launch_bounds__(256, 4)
attn_kern(const __bf16* __restrict__ q, const __bf16* __restrict__ k,
          const __bf16* __restrict__ vT, __bf16* __restrict__ o)
{
    __shared__ __align__(16) __bf16 Ks[64][72];
    __shared__ __align__(16) __bf16 Vs[64][72];
    __shared__ __align__(16) __bf16 Ps[4][16][72];
    const int tid = threadIdx.x, w = tid >> 6, lane = tid & 63;
    const int r = lane & 15, g = lane >> 4;
    const int bh = blockIdx.y;
    const int b = bh >> 4, h = bh & 15;
    const int xq = (int)gridDim.x - 1 - (int)blockIdx.x;   // LPT: heavy blocks first
    const int qb0 = xq << 6;
    const __bf16* qh  = q  + ((size_t)bh << 17);  // [2048][64]
    const __bf16* khp = k  + ((size_t)bh << 17);
    const __bf16* vhp = vT + ((size_t)bh << 17);  // [64][2048]

    const int wrow0 = qb0 + w * 16;               // wave's first q-row

    bf16x8 qf[2];
    #pragma unroll
    for (int kc = 0; kc < 2; ++kc)
        qf[kc] = *(const bf16x8*)&qh[(size_t)(wrow0 + r) * 64 + kc * 32 + g * 8];

    f32x4 oacc[4] = {};
    float mrun[4], lrun[4];
    #pragma unroll
    for (int j = 0; j < 4; ++j) { mrun[j] = -3.0e38f; lrun[j] = 0.f; }

    // staging coords: 256 threads stage a 64x64 tile in 2 rounds of bf16x8 chunks
    const int srow0 = tid >> 3, sci = tid & 7;    // rows 0..31 (round 0), +32 (round 1)
    // prologue: stage tile 0
    #pragma unroll
    for (int it = 0; it < 2; ++it) {
        int row = srow0 + it * 32;
        *(bf16x8*)&Ks[row][sci * 8] = *(const bf16x8*)&khp[(size_t)row * 64 + sci * 8];
        *(bf16x8*)&Vs[row][sci * 8] = *(const bf16x8*)&vhp[(size_t)row * 2048 + sci * 8];
    }
    __syncthreads();

    const int ntiles = xq + 1;
    for (int t = 0; t < ntiles; ++t) {
        const int n0 = t << 6;
        const bool pre = (t + 1 < ntiles);
        bf16x8 nk[2], nv[2];
        if (pre) {   // issue next tile's loads now; HBM latency hides under compute
            int n1 = n0 + 64;
            #pragma unroll
            for (int it = 0; it < 2; ++it) {
                int row = srow0 + it * 32;
                nk[it] = *(const bf16x8*)&khp[(size_t)(n1 + row) * 64 + sci * 8];
                nv[it] = *(const bf16x8*)&vhp[(size_t)row * 2048 + n1 + sci * 8];
            }
        }
        {
            f32x4 sacc[4] = {};
            #pragma unroll
            for (int kc = 0; kc < 2; ++kc) {
                bf16x8 kf[4];
                #pragma unroll
                for (int ni = 0; ni < 4; ++ni) kf[ni] = *(const bf16x8*)&Ks[ni * 16 + r][kc * 32 + g * 8];
                #pragma unroll
                for (int ni = 0; ni < 4; ++ni)
                    sacc[ni] = __builtin_amdgcn_mfma_f32_16x16x32_bf16(
                        qf[kc], kf[ni], sacc[ni], 0, 0, 0);
            }
            if (n0 + 63 > wrow0) {   // wave-uniform: tile touches the diagonal
                int rowa = wrow0 + g * 4;
                #pragma unroll
                for (int ni = 0; ni < 4; ++ni) {
                    int cola = n0 + ni * 16 + r;
                    #pragma unroll
                    for (int j = 0; j < 4; ++j)
                        if (cola > rowa + j) sacc[ni][j] = -3.0e38f;
                }
            }
            float fac[4];
            #pragma unroll
            for (int j = 0; j < 4; ++j) {
                float rm = fmaxf(fmaxf(sacc[0][j], sacc[1][j]),
                                 fmaxf(sacc[2][j], sacc[3][j]));
                rm = fmaxf(rm, __shfl_xor(rm, 1));
                rm = fmaxf(rm, __shfl_xor(rm, 2));
                rm = fmaxf(rm, __shfl_xor(rm, 4));
                rm = fmaxf(rm, __shfl_xor(rm, 8));
                float mnew = fmaxf(mrun[j], rm);
                float f = exp2f((mrun[j] - mnew) * SM_SC);
                float ps = 0.f;
                #pragma unroll
                for (int ni = 0; ni < 4; ++ni) {
                    float pv = exp2f((sacc[ni][j] - mnew) * SM_SC);
                    sacc[ni][j] = pv;
                    ps += pv;
                }
                ps += __shfl_xor(ps, 1); ps += __shfl_xor(ps, 2);
                ps += __shfl_xor(ps, 4); ps += __shfl_xor(ps, 8);
                lrun[j] = lrun[j] * f + ps;
                mrun[j] = mnew;
                fac[j] = f;
            }
            #pragma unroll
            for (int ni = 0; ni < 4; ++ni)
                #pragma unroll
                for (int j = 0; j < 4; ++j)
                    Ps[w][g * 4 + j][ni * 16 + r] = (__bf16)sacc[ni][j];
            #pragma unroll
            for (int di = 0; di < 4; ++di)
                #pragma unroll
                for (int j = 0; j < 4; ++j)
                    oacc[di][j] *= fac[j];
            // Ps is wave-private: no barrier needed before PV (lgkmcnt only)
            #pragma unroll
            for (int kc = 0; kc < 2; ++kc) {
                bf16x8 pf, vf[4];
                pf = *(const bf16x8*)&Ps[w][r][kc * 32 + g * 8];
                #pragma unroll
                for (int di = 0; di < 4; ++di) vf[di] = *(const bf16x8*)&Vs[di * 16 + r][kc * 32 + g * 8];
                #pragma unroll
                for (int di = 0; di < 4; ++di)
                    oacc[di] = __builtin_amdgcn_mfma_f32_16x16x32_bf16(
                        pf, vf[di], oacc[di], 0, 0, 0);
            }
        }
        __syncthreads();
        if (pre) {
            #pragma unroll
            for (int it = 0; it < 2; ++it) {
                int row = srow0 + it * 32;
                *(bf16x8*)&Ks[row][sci * 8] = nk[it];
                *(bf16x8*)&Vs[row][sci * 8] = nv[it];
            }
        }
        __syncthreads();
    }
    #pragma unroll
    for (int j = 0; j < 4; ++j) {
        float inv = 1.0f / lrun[j];
        int sr = wrow0 + g * 4 + j;
        #pragma unroll
        for (int di = 0; di < 4; ++di)
            o[((size_t)(b * 2048 + sr) << 10) + h * 64 + di * 16 + r] =
                (__bf16)(oacc[di][j] * inv);
    }
}

// ---------------- launch ----------------
extern "C" void kernel_launch(void* const* d_in, const int* in_sizes, int n_in,
                              void* d_out, int out_size, void* d_ws, size_t ws_size,
                              hipStream_t stream) {
    const float* x  = (const float*)d_in[0];
    const float* Wq = (const float*)d_in[1];
    const float* bq = (const float*)d_in[2];
    const float* Wk = (const float*)d_in[3];
    const float* bk = (const float*)d_in[4];
    const float* Wv = (const float*)d_in[5];
    const float* bv = (const float*)d_in[6];
    const float* Wo = (const float*)d_in[7];
    const float* bo = (const float*)d_in[8];
    float* out = (float*)d_out;
    char* ws = (char*)d_ws;
    // workspace layout (bytes), total ~48 MB
    __bf16* xb    = (__bf16*)(ws + 0);          //  8 MB  x as bf16 [4096][1024]
    __bf16* wtqkv = (__bf16*)(ws + 8388608);    //  6 MB  fused qkv weights^T [3072][1024]
    __bf16* wot   = (__bf16*)(ws + 14680064);   //  2 MB  W_o^T [1024][1024]
    float*  biasq = (float*) (ws + 16777216);   // 12 KB  fused qkv bias
    __bf16* qb    = (__bf16*)(ws + 16793600);   //  8 MB  q [32][2048][64]
    __bf16* kb    = (__bf16*)(ws + 25182208);   //  8 MB  k [32][2048][64]
    __bf16* vtb   = (__bf16*)(ws + 33570816);   //  8 MB  v^T [32][64][2048]
    __bf16* ob    = (__bf16*)(ws + 41959424);   //  8 MB  attn out [4096][1024]

    prep_x_kern<<<4096, 256, 0, stream>>>(x, xb);
    prep_wqkv_kern<<<12288, 256, 0, stream>>>(Wq, Wk, Wv, bq, bk, bv, wtqkv, biasq);
    prep_wo_kern<<<4096, 256, 0, stream>>>(Wo, wot);
    gemm_bt<0><<<dim3(24, 32), 256, 0, stream>>>(xb, wtqkv, biasq, qb, kb, vtb, nullptr);
    attn_kern<<<dim3(32, 32), 256, 0, stream>>>(qb, kb, vtb, ob);
    gemm_bt<1><<<dim3(8, 32), 256, 0, stream>>>(ob, wot, bo, nullptr, nullptr, nullptr, out);
}

// Round 4
// 170.832 us; speedup vs baseline: 1.2278x; 1.2278x over previous
//
#include <hip/hip_runtime.h>

// B=2, S=2048, E=1024, H=16, D=64.  M = B*S = 4096.
// Pipeline: prep (f32->bf16 + weight transposes) -> GEMM1 (QKV, writes q/k [bh][s][d],
// v transposed [bh][d][s]) -> flash attention (writes o [m][1024] bf16) -> GEMM3 (f32 out).

typedef __attribute__((ext_vector_type(8)))  __bf16 bf16x8;
typedef __attribute__((ext_vector_type(4)))  __bf16 bf16x4;
typedef __attribute__((ext_vector_type(2)))  __bf16 bf16x2;
typedef __attribute__((ext_vector_type(4)))  float  f32x4;
typedef __attribute__((ext_vector_type(16))) float  f32x16;

#define LOG2E 1.4426950408889634f
#define SM_SC (0.125f * LOG2E)   // softmax scale folded with log2(e)

static __device__ __forceinline__ void gl2lds16(const void* g, void* l) {
    __builtin_amdgcn_global_load_lds(
        (__attribute__((address_space(1))) void*)(void*)g,
        (__attribute__((address_space(3))) void*)l, 16, 0, 0);
}

// ---------------- prep kernels ----------------
__global__ void prep_x_kern(const float* __restrict__ x, __bf16* __restrict__ xb) {
    int i = (blockIdx.x * 256 + threadIdx.x) * 4;
    f32x4 v = *(const f32x4*)(x + i);
    bf16x4 o = { (__bf16)v[0], (__bf16)v[1], (__bf16)v[2], (__bf16)v[3] };
    *(bf16x4*)(xb + i) = o;
}

// wt[n][k] = W_p[h][k][d],  n = p*1024 + h*64 + d (p in {q,k,v}); bias[n] = b_p[h*64+d]
__global__ void prep_wqkv_kern(const float* __restrict__ Wq, const float* __restrict__ Wk,
                               const float* __restrict__ Wv, const float* __restrict__ bq,
                               const float* __restrict__ bk, const float* __restrict__ bv,
                               __bf16* __restrict__ wt, float* __restrict__ bias) {
    int idx = blockIdx.x * 256 + threadIdx.x;     // 0..3145727
    int n = idx >> 10, kk = idx & 1023;
    int p = n >> 10, rm = n & 1023;
    int h = rm >> 6, d = rm & 63;
    const float* W = (p == 0) ? Wq : (p == 1) ? Wk : Wv;
    wt[idx] = (__bf16)W[(h << 16) + (kk << 6) + d];
    if (idx < 3072) {
        int p2 = idx >> 10, rm2 = idx & 1023;
        const float* bb = (p2 == 0) ? bq : (p2 == 1) ? bk : bv;
        bias[idx] = bb[rm2];
    }
}

// wt[n][k] = W_o[k][n]
__global__ void prep_wo_kern(const float* __restrict__ Wo, __bf16* __restrict__ wt) {
    int idx = blockIdx.x * 256 + threadIdx.x;    // 0..1048575
    int n = idx >> 10, kk = idx & 1023;
    wt[idx] = (__bf16)Wo[(kk << 10) + n];
}

// ---------------- GEMM: C[M][N] = A[M][1024] * Bt[N][1024]^T (+bias) ----------------
// 128x128 tile, BK=64, 4 waves each computing 64x64 via 4x4 of 16x16x32 MFMA.
// EPI=0: scatter bf16 into q/k ([bh][s][d]) and vT ([bh][d][s]) per n = p*1024+h*64+d
// EPI=1: f32 out + bias
template <int EPI>
__global__ void __launch_bounds__(256, 2)
gemm_bt(const __bf16* __restrict__ A, const __bf16* __restrict__ Bt,
        const float* __restrict__ bias,
        __bf16* __restrict__ outq, __bf16* __restrict__ outk, __bf16* __restrict__ outv,
        float* __restrict__ outf)
{
    __shared__ __align__(16) __bf16 As[128 * 64];
    __shared__ __align__(16) __bf16 Bs[128 * 64];
    const int tid = threadIdx.x;
    const int wid = tid >> 6, lane = tid & 63;
    const int r = lane & 15, g = lane >> 4;
    const int m0 = blockIdx.y << 7, n0 = blockIdx.x << 7;
    const int wr = wid >> 1, wc = wid & 1;
    f32x4 acc[4][4] = {};
    for (int k0 = 0; k0 < 1024; k0 += 64) {
        #pragma unroll
        for (int c = 0; c < 4; ++c) {
            int cq = (c * 4 + wid) * 64 + lane;   // 16B chunk index in [0,1024)
            int row = cq >> 3, ci = cq & 7;
            gl2lds16(A  + (((size_t)(m0 + row)) << 10) + k0 + ci * 8, As + (c * 4 + wid) * 512);
            gl2lds16(Bt + (((size_t)(n0 + row)) << 10) + k0 + ci * 8, Bs + (c * 4 + wid) * 512);
        }
        __syncthreads();
        bf16x8 af[2][4], bfr[2][4];
        #pragma unroll
        for (int kh = 0; kh < 2; ++kh)
            #pragma unroll
            for (int i = 0; i < 4; ++i) {
                af[kh][i]  = *(const bf16x8*)&As[(wr * 64 + i * 16 + r) * 64 + kh * 32 + g * 8];
                bfr[kh][i] = *(const bf16x8*)&Bs[(wc * 64 + i * 16 + r) * 64 + kh * 32 + g * 8];
            }
        #pragma unroll
        for (int kh = 0; kh < 2; ++kh)
            #pragma unroll
            for (int mi = 0; mi < 4; ++mi)
                #pragma unroll
                for (int ni = 0; ni < 4; ++ni)
                    acc[mi][ni] = __builtin_amdgcn_mfma_f32_16x16x32_bf16(
                        af[kh][mi], bfr[kh][ni], acc[mi][ni], 0, 0, 0);
        __syncthreads();
    }
    if (EPI == 0) {
        #pragma unroll
        for (int ni = 0; ni < 4; ++ni) {
            int n = n0 + wc * 64 + ni * 16 + r;
            float bv = bias[n];
            int p = n >> 10, rem = n & 1023, h = rem >> 6, d = rem & 63;
            #pragma unroll
            for (int mi = 0; mi < 4; ++mi) {
                int mb = m0 + wr * 64 + mi * 16 + g * 4;
                int b = mb >> 11, s = mb & 2047;
                f32x4 v = acc[mi][ni];
                if (p < 2) {
                    __bf16* dst = (p == 0) ? outq : outk;
                    size_t base = (((size_t)(b * 16 + h)) * 2048 + s) * 64 + d;
                    #pragma unroll
                    for (int j = 0; j < 4; ++j)
                        dst[base + (size_t)j * 64] = (__bf16)(v[j] + bv);
                } else {
                    bf16x4 pk = { (__bf16)(v[0] + bv), (__bf16)(v[1] + bv),
                                  (__bf16)(v[2] + bv), (__bf16)(v[3] + bv) };
                    *(bf16x4*)&outv[(((size_t)(b * 16 + h)) * 64 + d) * 2048 + s] = pk;
                }
            }
        }
    } else {
        #pragma unroll
        for (int ni = 0; ni < 4; ++ni) {
            int n = n0 + wc * 64 + ni * 16 + r;
            float bv = bias[n];
            #pragma unroll
            for (int mi = 0; mi < 4; ++mi) {
                int mb = m0 + wr * 64 + mi * 16 + g * 4;
                f32x4 v = acc[mi][ni];
                #pragma unroll
                for (int j = 0; j < 4; ++j)
                    outf[((size_t)(mb + j) << 10) + n] = v[j] + bv;
            }
        }
    }
}

// ---------------- flash attention (swapped-operand 32x32x16) ----------------
// grid (16, 32): x = 128-row Q-block (reversed, LPT), y = b*16+h.
// 4 waves x 32 q-rows. Swapped QK^T: mfma(K, Q) -> S^T, lane owns q-row m=lane&31,
// 32 S-values in regs -> softmax is in-lane + 2 shfl_xor(32). PV swapped too:
// mfma(V^T, P^T) -> O^T, col=m stays lane-local so rescale needs no broadcast.
// K tile [64 n][64 d], V^T tile [64 d][64 n] in padded LDS; P packed bf16x2 via LDS.
__global__ void __launch_bounds__(256)
attn_kern(const __bf16* __restrict__ q, const __bf16* __restrict__ k,
          const __bf16* __restrict__ vT, __bf16* __restrict__ o)
{
    __shared__ __align__(16) __bf16 Ks [64][72];
    __shared__ __align__(16) __bf16 VsT[64][72];
    __shared__ __align__(16) __bf16 Ps [4][32][72];
    const int tid = threadIdx.x, w = tid >> 6, lane = tid & 63;
    const int r31 = lane & 31, hi = lane >> 5;
    const int bh = blockIdx.y, b = bh >> 4, h = bh & 15;
    const int xq = (int)gridDim.x - 1 - (int)blockIdx.x;   // LPT: heavy blocks first
    const int qb0 = xq << 7;
    const __bf16* qh  = q  + ((size_t)bh << 17);  // [2048][64]
    const __bf16* khp = k  + ((size_t)bh << 17);
    const __bf16* vhp = vT + ((size_t)bh << 17);  // [64][2048]
    const int wrow0 = qb0 + w * 32;
    const int mg = wrow0 + r31;                   // this lane's q-row

    // Q fragments (B-operand): lane needs Q[mg][kk*16 + hi*8 + e]
    bf16x8 qf[4];
    #pragma unroll
    for (int kk = 0; kk < 4; ++kk)
        qf[kk] = *(const bf16x8*)&qh[(size_t)mg * 64 + kk * 16 + hi * 8];

    f32x16 oacc[2] = {};
    float mrun = -3.0e38f, lrun = 0.f;

    const int srow = tid >> 3, sci = tid & 7;     // staging: 2 rounds x 32 rows
    #pragma unroll
    for (int it = 0; it < 2; ++it) {
        int row = srow + it * 32;
        *(bf16x8*)&Ks [row][sci * 8] = *(const bf16x8*)&khp[(size_t)row * 64 + sci * 8];
        *(bf16x8*)&VsT[row][sci * 8] = *(const bf16x8*)&vhp[(size_t)row * 2048 + sci * 8];
    }
    __syncthreads();

    const int ntiles = (qb0 >> 6) + 2;
    for (int t = 0; t < ntiles; ++t) {
        const int n0 = t << 6;
        const bool pre = (t + 1 < ntiles);
        bf16x8 nk[2], nv[2];
        if (pre) {   // issue next tile's loads; latency hides under compute
            int n1 = n0 + 64;
            #pragma unroll
            for (int it = 0; it < 2; ++it) {
                int row = srow + it * 32;
                nk[it] = *(const bf16x8*)&khp[(size_t)(n1 + row) * 64 + sci * 8];
                nv[it] = *(const bf16x8*)&vhp[(size_t)row * 2048 + n1 + sci * 8];
            }
        }
        if (n0 <= wrow0 + 31) {                   // wave-uniform activity guard
            // ---- QK^T (swapped): sacc = S^T fragments ----
            f32x16 sacc[2] = {};
            #pragma unroll
            for (int kk = 0; kk < 4; ++kk) {
                bf16x8 kf0 = *(const bf16x8*)&Ks[r31]     [kk * 16 + hi * 8];
                bf16x8 kf1 = *(const bf16x8*)&Ks[32 + r31][kk * 16 + hi * 8];
                sacc[0] = __builtin_amdgcn_mfma_f32_32x32x16_bf16(kf0, qf[kk], sacc[0], 0, 0, 0);
                sacc[1] = __builtin_amdgcn_mfma_f32_32x32x16_bf16(kf1, qf[kk], sacc[1], 0, 0, 0);
            }
            // ---- causal mask (diagonal-touching tiles only) ----
            if (n0 + 63 > wrow0) {
                #pragma unroll
                for (int nf = 0; nf < 2; ++nf)
                    #pragma unroll
                    for (int i = 0; i < 16; ++i) {
                        int n = n0 + nf * 32 + (i & 3) + 8 * (i >> 2) + 4 * hi;
                        if (n > mg) sacc[nf][i] = -3.0e38f;
                    }
            }
            // ---- online softmax: in-lane + 2 cross-half shuffles ----
            float pm = sacc[0][0];
            #pragma unroll
            for (int nf = 0; nf < 2; ++nf)
                #pragma unroll
                for (int i = 0; i < 16; ++i) pm = fmaxf(pm, sacc[nf][i]);
            pm = fmaxf(pm, __shfl_xor(pm, 32));
            float mnew = fmaxf(mrun, pm);
            float fac = exp2f((mrun - mnew) * SM_SC);
            float sum = 0.f;
            #pragma unroll
            for (int nf = 0; nf < 2; ++nf)
                #pragma unroll
                for (int i = 0; i < 16; ++i) {
                    float pv = exp2f((sacc[nf][i] - mnew) * SM_SC);
                    sacc[nf][i] = pv;
                    sum += pv;
                }
            sum += __shfl_xor(sum, 32);
            lrun = lrun * fac + sum;
            mrun = mnew;
            // ---- pack P to bf16 pairs, write wave-private Ps[m][n] ----
            #pragma unroll
            for (int nf = 0; nf < 2; ++nf)
                #pragma unroll
                for (int qd = 0; qd < 8; ++qd) {
                    bf16x2 pr = { (__bf16)sacc[nf][2 * qd], (__bf16)sacc[nf][2 * qd + 1] };
                    int dw = nf * 16 + 4 * (qd >> 1) + 2 * hi + (qd & 1);
                    ((bf16x2*)&Ps[w][r31][0])[dw] = pr;
                }
            // ---- rescale O^T (fac is lane-local), then PV (swapped) ----
            #pragma unroll
            for (int df = 0; df < 2; ++df)
                #pragma unroll
                for (int i = 0; i < 16; ++i) oacc[df][i] *= fac;
            #pragma unroll
            for (int kk2 = 0; kk2 < 4; ++kk2) {
                bf16x8 pf  = *(const bf16x8*)&Ps[w][r31][kk2 * 16 + hi * 8];
                bf16x8 af0 = *(const bf16x8*)&VsT[r31]     [kk2 * 16 + hi * 8];
                bf16x8 af1 = *(const bf16x8*)&VsT[32 + r31][kk2 * 16 + hi * 8];
                oacc[0] = __builtin_amdgcn_mfma_f32_32x32x16_bf16(af0, pf, oacc[0], 0, 0, 0);
                oacc[1] = __builtin_amdgcn_mfma_f32_32x32x16_bf16(af1, pf, oacc[1], 0, 0, 0);
            }
        }
        __syncthreads();
        if (pre) {
            #pragma unroll
            for (int it = 0; it < 2; ++it) {
                int row = srow + it * 32;
                *(bf16x8*)&Ks [row][sci * 8] = nk[it];
                *(bf16x8*)&VsT[row][sci * 8] = nv[it];
            }
        }
        __syncthreads();
    }
    // ---- epilogue: O^T regs -> o[m][h*64+d], lane owns column m=mg ----
    float inv = 1.0f / lrun;
    #pragma unroll
    for (int df = 0; df < 2; ++df)
        #pragma unroll
        for (int td = 0; td < 8; ++td) {
            bf16x2 pr = { (__bf16)(oacc[df][2 * td] * inv),
                          (__bf16)(oacc[df][2 * td + 1] * inv) };
            int d = df * 32 + 8 * (td >> 1) + 4 * hi + 2 * (td & 1);
            *(bf16x2*)&o[((size_t)(b * 2048 + mg) << 10) + h * 64 + d] = pr;
        }
}

// ---------------- launch ----------------
extern "C" void kernel_launch(void* const* d_in, const int* in_sizes, int n_in,
                              void* d_out, int out_size, void* d_ws, size_t ws_size,
                              hipStream_t stream) {
    const float* x  = (const float*)d_in[0];
    const float* Wq = (const float*)d_in[1];
    const float* bq = (const float*)d_in[2];
    const float* Wk = (const float*)d_in[3];
    const float* bk = (const float*)d_in[4];
    const float* Wv = (const float*)d_in[5];
    const float* bv = (const float*)d_in[6];
    const float* Wo = (const float*)d_in[7];
    const float* bo = (const float*)d_in[8];
    float* out = (float*)d_out;
    char* ws = (char*)d_ws;
    // workspace layout (bytes), total ~48 MB
    __bf16* xb    = (__bf16*)(ws + 0);          //  8 MB  x as bf16 [4096][1024]
    __bf16* wtqkv = (__bf16*)(ws + 8388608);    //  6 MB  fused qkv weights^T [3072][1024]
    __bf16* wot   = (__bf16*)(ws + 14680064);   //  2 MB  W_o^T [1024][1024]
    float*  biasq = (float*) (ws + 16777216);   // 12 KB  fused qkv bias
    __bf16* qb    = (__bf16*)(ws + 16793600);   //  8 MB  q [32][2048][64]
    __bf16* kb    = (__bf16*)(ws + 25182208);   //  8 MB  k [32][2048][64]
    __bf16* vtb   = (__bf16*)(ws + 33570816);   //  8 MB  v^T [32][64][2048]
    __bf16* ob    = (__bf16*)(ws + 41959424);   //  8 MB  attn out [4096][1024]

    prep_x_kern<<<4096, 256, 0, stream>>>(x, xb);
    prep_wqkv_kern<<<12288, 256, 0, stream>>>(Wq, Wk, Wv, bq, bk, bv, wtqkv, biasq);
    prep_wo_kern<<<4096, 256, 0, stream>>>(Wo, wot);
    gemm_bt<0><<<dim3(24, 32), 256, 0, stream>>>(xb, wtqkv, biasq, qb, kb, vtb, nullptr);
    attn_kern<<<dim3(16, 32), 256, 0, stream>>>(qb, kb, vtb, ob);
    gemm_bt<1><<<dim3(8, 32), 256, 0, stream>>>(ob, wot, bo, nullptr, nullptr, nullptr, out);
}

// Round 5
// 159.394 us; speedup vs baseline: 1.3159x; 1.0718x over previous
//
#include <hip/hip_runtime.h>

// B=2, S=2048, E=1024, H=16, D=64.  M = B*S = 4096.
// Pipeline: prep (f32->bf16 + weight transposes) -> GEMM1 (QKV, writes q/k [bh][s][d],
// v transposed [bh][d][s]) -> flash attention (writes o [m][1024] bf16) -> GEMM3 (f32 out).

typedef __attribute__((ext_vector_type(8)))  __bf16 bf16x8;
typedef __attribute__((ext_vector_type(4)))  __bf16 bf16x4;
typedef __attribute__((ext_vector_type(2)))  __bf16 bf16x2;
typedef __attribute__((ext_vector_type(4)))  float  f32x4;
typedef __attribute__((ext_vector_type(16))) float  f32x16;

#define LOG2E 1.4426950408889634f
#define SM_SC (0.125f * LOG2E)   // softmax scale folded with log2(e)

static __device__ __forceinline__ void gl2lds16(const void* g, void* l) {
    __builtin_amdgcn_global_load_lds(
        (__attribute__((address_space(1))) void*)(void*)g,
        (__attribute__((address_space(3))) void*)l, 16, 0, 0);
}

// ---------------- prep kernels ----------------
__global__ void prep_x_kern(const float* __restrict__ x, __bf16* __restrict__ xb) {
    int i = (blockIdx.x * 256 + threadIdx.x) * 4;
    f32x4 v = *(const f32x4*)(x + i);
    bf16x4 o = { (__bf16)v[0], (__bf16)v[1], (__bf16)v[2], (__bf16)v[3] };
    *(bf16x4*)(xb + i) = o;
}

// wt[n][k] = W_p[h][k][d],  n = p*1024 + h*64 + d (p in {q,k,v}); bias[n] = b_p[h*64+d]
__global__ void prep_wqkv_kern(const float* __restrict__ Wq, const float* __restrict__ Wk,
                               const float* __restrict__ Wv, const float* __restrict__ bq,
                               const float* __restrict__ bk, const float* __restrict__ bv,
                               __bf16* __restrict__ wt, float* __restrict__ bias) {
    int idx = blockIdx.x * 256 + threadIdx.x;     // 0..3145727
    int n = idx >> 10, kk = idx & 1023;
    int p = n >> 10, rm = n & 1023;
    int h = rm >> 6, d = rm & 63;
    const float* W = (p == 0) ? Wq : (p == 1) ? Wk : Wv;
    wt[idx] = (__bf16)W[(h << 16) + (kk << 6) + d];
    if (idx < 3072) {
        int p2 = idx >> 10, rm2 = idx & 1023;
        const float* bb = (p2 == 0) ? bq : (p2 == 1) ? bk : bv;
        bias[idx] = bb[rm2];
    }
}

// wt[n][k] = W_o[k][n]
__global__ void prep_wo_kern(const float* __restrict__ Wo, __bf16* __restrict__ wt) {
    int idx = blockIdx.x * 256 + threadIdx.x;    // 0..1048575
    int n = idx >> 10, kk = idx & 1023;
    wt[idx] = (__bf16)Wo[(kk << 10) + n];
}

// ---------------- GEMM: C[M][N] = A[M][1024] * Bt[N][1024]^T (+bias) ----------------
// 128x128 tile, BK=64, 4 waves each computing 64x64 via 4x4 of 16x16x32 MFMA.
// EPI=0: scatter bf16 into q/k ([bh][s][d]) and vT ([bh][d][s]) per n = p*1024+h*64+d
// EPI=1: f32 out + bias
template <int EPI>
__global__ void __launch_bounds__(256, 2)
gemm_bt(const __bf16* __restrict__ A, const __bf16* __restrict__ Bt,
        const float* __restrict__ bias,
        __bf16* __restrict__ outq, __bf16* __restrict__ outk, __bf16* __restrict__ outv,
        float* __restrict__ outf)
{
    __shared__ __align__(16) __bf16 As[128 * 64];
    __shared__ __align__(16) __bf16 Bs[128 * 64];
    const int tid = threadIdx.x;
    const int wid = tid >> 6, lane = tid & 63;
    const int r = lane & 15, g = lane >> 4;
    const int m0 = blockIdx.y << 7, n0 = blockIdx.x << 7;
    const int wr = wid >> 1, wc = wid & 1;
    f32x4 acc[4][4] = {};
    for (int k0 = 0; k0 < 1024; k0 += 64) {
        #pragma unroll
        for (int c = 0; c < 4; ++c) {
            int cq = (c * 4 + wid) * 64 + lane;   // 16B chunk index in [0,1024)
            int row = cq >> 3, ci = cq & 7;
            gl2lds16(A  + (((size_t)(m0 + row)) << 10) + k0 + ci * 8, As + (c * 4 + wid) * 512);
            gl2lds16(Bt + (((size_t)(n0 + row)) << 10) + k0 + ci * 8, Bs + (c * 4 + wid) * 512);
        }
        __syncthreads();
        bf16x8 af[2][4], bfr[2][4];
        #pragma unroll
        for (int kh = 0; kh < 2; ++kh)
            #pragma unroll
            for (int i = 0; i < 4; ++i) {
                af[kh][i]  = *(const bf16x8*)&As[(wr * 64 + i * 16 + r) * 64 + kh * 32 + g * 8];
                bfr[kh][i] = *(const bf16x8*)&Bs[(wc * 64 + i * 16 + r) * 64 + kh * 32 + g * 8];
            }
        #pragma unroll
        for (int kh = 0; kh < 2; ++kh)
            #pragma unroll
            for (int mi = 0; mi < 4; ++mi)
                #pragma unroll
                for (int ni = 0; ni < 4; ++ni)
                    acc[mi][ni] = __builtin_amdgcn_mfma_f32_16x16x32_bf16(
                        af[kh][mi], bfr[kh][ni], acc[mi][ni], 0, 0, 0);
        __syncthreads();
    }
    if (EPI == 0) {
        #pragma unroll
        for (int ni = 0; ni < 4; ++ni) {
            int n = n0 + wc * 64 + ni * 16 + r;
            float bv = bias[n];
            int p = n >> 10, rem = n & 1023, h = rem >> 6, d = rem & 63;
            #pragma unroll
            for (int mi = 0; mi < 4; ++mi) {
                int mb = m0 + wr * 64 + mi * 16 + g * 4;
                int b = mb >> 11, s = mb & 2047;
                f32x4 v = acc[mi][ni];
                if (p < 2) {
                    __bf16* dst = (p == 0) ? outq : outk;
                    size_t base = (((size_t)(b * 16 + h)) * 2048 + s) * 64 + d;
                    #pragma unroll
                    for (int j = 0; j < 4; ++j)
                        dst[base + (size_t)j * 64] = (__bf16)(v[j] + bv);
                } else {
                    bf16x4 pk = { (__bf16)(v[0] + bv), (__bf16)(v[1] + bv),
                                  (__bf16)(v[2] + bv), (__bf16)(v[3] + bv) };
                    *(bf16x4*)&outv[(((size_t)(b * 16 + h)) * 64 + d) * 2048 + s] = pk;
                }
            }
        }
    } else {
        #pragma unroll
        for (int ni = 0; ni < 4; ++ni) {
            int n = n0 + wc * 64 + ni * 16 + r;
            float bv = bias[n];
            #pragma unroll
            for (int mi = 0; mi < 4; ++mi) {
                int mb = m0 + wr * 64 + mi * 16 + g * 4;
                f32x4 v = acc[mi][ni];
                #pragma unroll
                for (int j = 0; j < 4; ++j)
                    outf[((size_t)(mb + j) << 10) + n] = v[j] + bv;
            }
        }
    }
}

// ---------------- flash attention (swapped 32x32x16, pair-balanced) ----------------
// grid (8, 32): block handles Q-blocks {15-bx, bx} sequentially -> uniform 34 KV
// tiles per block. 4 waves x 32 q-rows. Swapped QK^T: mfma(K,Q) -> lane owns q-row,
// softmax in-lane (tree reductions) + 2 shfl_xor(32). Defer-max rescale (THR=2^8).
// Double-buffered K/V LDS -> single barrier per tile; P via wave-private LDS.
__global__ void __launch_bounds__(256)
attn_kern(const __bf16* __restrict__ q, const __bf16* __restrict__ k,
          const __bf16* __restrict__ vT, __bf16* __restrict__ o)
{
    __shared__ __align__(16) __bf16 Ks [2][64][72];
    __shared__ __align__(16) __bf16 VsT[2][64][72];
    __shared__ __align__(16) __bf16 Ps [4][32][72];
    const int tid = threadIdx.x, w = tid >> 6, lane = tid & 63;
    const int r31 = lane & 31, hi = lane >> 5;
    const int bh = blockIdx.y, b = bh >> 4, h = bh & 15;
    const __bf16* qh  = q  + ((size_t)bh << 17);  // [2048][64]
    const __bf16* khp = k  + ((size_t)bh << 17);
    const __bf16* vhp = vT + ((size_t)bh << 17);  // [64][2048]
    const int srow = tid >> 3, sci = tid & 7;     // staging: 2 rounds x 32 rows

    for (int seg = 0; seg < 2; ++seg) {
        const int xq = (seg == 0) ? (15 - (int)blockIdx.x) : (int)blockIdx.x;
        const int qb0 = xq << 7;
        const int wrow0 = qb0 + w * 32;
        const int mg = wrow0 + r31;               // this lane's q-row

        bf16x8 qf[4];
        #pragma unroll
        for (int kk = 0; kk < 4; ++kk)
            qf[kk] = *(const bf16x8*)&qh[(size_t)mg * 64 + kk * 16 + hi * 8];

        f32x16 oacc[2] = {};
        float mrun = -3.0e38f, lrun = 0.f;

        // stage tile 0 into buffer 0
        #pragma unroll
        for (int it = 0; it < 2; ++it) {
            int row = srow + it * 32;
            *(bf16x8*)&Ks [0][row][sci * 8] = *(const bf16x8*)&khp[(size_t)row * 64 + sci * 8];
            *(bf16x8*)&VsT[0][row][sci * 8] = *(const bf16x8*)&vhp[(size_t)row * 2048 + sci * 8];
        }
        __syncthreads();

        const int nt = (qb0 >> 6) + 2;            // even
        for (int t = 0; t < nt; ++t) {
            const int cur = t & 1, nxt = cur ^ 1;
            const int n0 = t << 6;
            const bool pre = (t + 1 < nt);
            bf16x8 nk[2], nv[2];
            if (pre) {   // issue next tile's loads; consumed after compute
                int n1 = n0 + 64;
                #pragma unroll
                for (int it = 0; it < 2; ++it) {
                    int row = srow + it * 32;
                    nk[it] = *(const bf16x8*)&khp[(size_t)(n1 + row) * 64 + sci * 8];
                    nv[it] = *(const bf16x8*)&vhp[(size_t)row * 2048 + n1 + sci * 8];
                }
            }
            if (n0 <= wrow0 + 31) {               // wave-uniform activity guard
                // ---- QK^T (swapped): sacc = S^T fragments ----
                f32x16 sacc[2] = {};
                #pragma unroll
                for (int kk = 0; kk < 4; ++kk) {
                    bf16x8 kf0 = *(const bf16x8*)&Ks[cur][r31]     [kk * 16 + hi * 8];
                    bf16x8 kf1 = *(const bf16x8*)&Ks[cur][32 + r31][kk * 16 + hi * 8];
                    sacc[0] = __builtin_amdgcn_mfma_f32_32x32x16_bf16(kf0, qf[kk], sacc[0], 0, 0, 0);
                    sacc[1] = __builtin_amdgcn_mfma_f32_32x32x16_bf16(kf1, qf[kk], sacc[1], 0, 0, 0);
                }
                // ---- causal mask (diagonal-touching tiles only) ----
                if (n0 + 63 > wrow0) {
                    #pragma unroll
                    for (int nf = 0; nf < 2; ++nf)
                        #pragma unroll
                        for (int i = 0; i < 16; ++i) {
                            int n = n0 + nf * 32 + (i & 3) + 8 * (i >> 2) + 4 * hi;
                            if (n > mg) sacc[nf][i] = -3.0e38f;
                        }
                }
                // ---- row max: tree reduce (depth 5) + cross-half shuffle ----
                float mx[16];
                #pragma unroll
                for (int i = 0; i < 16; ++i) mx[i] = fmaxf(sacc[0][i], sacc[1][i]);
                #pragma unroll
                for (int s = 8; s > 0; s >>= 1)
                    #pragma unroll
                    for (int i = 0; i < 8; ++i)
                        if (i < s) mx[i] = fmaxf(mx[i], mx[i + s]);
                float pm = fmaxf(mx[0], __shfl_xor(mx[0], 32));
                // ---- defer-max: rescale only when max grew past threshold ----
                if (!__all((pm - mrun) * SM_SC <= 8.0f)) {
                    float mnew = fmaxf(mrun, pm);
                    float fac = exp2f((mrun - mnew) * SM_SC);
                    lrun *= fac;
                    #pragma unroll
                    for (int df = 0; df < 2; ++df)
                        #pragma unroll
                        for (int i = 0; i < 16; ++i) oacc[df][i] *= fac;
                    mrun = mnew;
                }
                // ---- P = exp2, sum via tree + cross-half shuffle ----
                #pragma unroll
                for (int nf = 0; nf < 2; ++nf)
                    #pragma unroll
                    for (int i = 0; i < 16; ++i)
                        sacc[nf][i] = exp2f((sacc[nf][i] - mrun) * SM_SC);
                float sm[16];
                #pragma unroll
                for (int i = 0; i < 16; ++i) sm[i] = sacc[0][i] + sacc[1][i];
                #pragma unroll
                for (int s = 8; s > 0; s >>= 1)
                    #pragma unroll
                    for (int i = 0; i < 8; ++i)
                        if (i < s) sm[i] += sm[i + s];
                lrun += sm[0] + __shfl_xor(sm[0], 32);
                // ---- pack P to bf16 pairs, write wave-private Ps[m][n] ----
                #pragma unroll
                for (int nf = 0; nf < 2; ++nf)
                    #pragma unroll
                    for (int qd = 0; qd < 8; ++qd) {
                        bf16x2 pr = { (__bf16)sacc[nf][2 * qd], (__bf16)sacc[nf][2 * qd + 1] };
                        int dw = nf * 16 + 4 * (qd >> 1) + 2 * hi + (qd & 1);
                        ((bf16x2*)&Ps[w][r31][0])[dw] = pr;
                    }
                // ---- PV (swapped): oacc += V^T x P^T ----
                #pragma unroll
                for (int kk2 = 0; kk2 < 4; ++kk2) {
                    bf16x8 pf  = *(const bf16x8*)&Ps[w][r31][kk2 * 16 + hi * 8];
                    bf16x8 af0 = *(const bf16x8*)&VsT[cur][r31]     [kk2 * 16 + hi * 8];
                    bf16x8 af1 = *(const bf16x8*)&VsT[cur][32 + r31][kk2 * 16 + hi * 8];
                    oacc[0] = __builtin_amdgcn_mfma_f32_32x32x16_bf16(af0, pf, oacc[0], 0, 0, 0);
                    oacc[1] = __builtin_amdgcn_mfma_f32_32x32x16_bf16(af1, pf, oacc[1], 0, 0, 0);
                }
            }
            if (pre) {   // write prefetched tile into the other buffer (no WAR hazard)
                #pragma unroll
                for (int it = 0; it < 2; ++it) {
                    int row = srow + it * 32;
                    *(bf16x8*)&Ks [nxt][row][sci * 8] = nk[it];
                    *(bf16x8*)&VsT[nxt][row][sci * 8] = nv[it];
                }
            }
            __syncthreads();                      // single barrier per tile
        }
        // ---- epilogue: O^T regs -> o[m][h*64+d], lane owns column m=mg ----
        float inv = 1.0f / lrun;
        #pragma unroll
        for (int df = 0; df < 2; ++df)
            #pragma unroll
            for (int td = 0; td < 8; ++td) {
                bf16x2 pr = { (__bf16)(oacc[df][2 * td] * inv),
                              (__bf16)(oacc[df][2 * td + 1] * inv) };
                int d = df * 32 + 8 * (td >> 1) + 4 * hi + 2 * (td & 1);
                *(bf16x2*)&o[((size_t)(b * 2048 + mg) << 10) + h * 64 + d] = pr;
            }
    }
}

// ---------------- launch ----------------
extern "C" void kernel_launch(void* const* d_in, const int* in_sizes, int n_in,
                              void* d_out, int out_size, void* d_ws, size_t ws_size,
                              hipStream_t stream) {
    const float* x  = (const float*)d_in[0];
    const float* Wq = (const float*)d_in[1];
    const float* bq = (const float*)d_in[2];
    const float* Wk = (const float*)d_in[3];
    const float* bk = (const float*)d_in[4];
    const float* Wv = (const float*)d_in[5];
    const float* bv = (const float*)d_in[6];
    const float* Wo = (const float*)d_in[7];
    const float* bo = (const float*)d_in[8];
    float* out = (float*)d_out;
    char* ws = (char*)d_ws;
    // workspace layout (bytes), total ~48 MB
    __bf16* xb    = (__bf16*)(ws + 0);          //  8 MB  x as bf16 [4096][1024]
    __bf16* wtqkv = (__bf16*)(ws + 8388608);    //  6 MB  fused qkv weights^T [3072][1024]
    __bf16* wot   = (__bf16*)(ws + 14680064);   //  2 MB  W_o^T [1024][1024]
    float*  biasq = (float*) (ws + 16777216);   // 12 KB  fused qkv bias
    __bf16* qb    = (__bf16*)(ws + 16793600);   //  8 MB  q [32][2048][64]
    __bf16* kb    = (__bf16*)(ws + 25182208);   //  8 MB  k [32][2048][64]
    __bf16* vtb   = (__bf16*)(ws + 33570816);   //  8 MB  v^T [32][64][2048]
    __bf16* ob    = (__bf16*)(ws + 41959424);   //  8 MB  attn out [4096][1024]

    prep_x_kern<<<4096, 256, 0, stream>>>(x, xb);
    prep_wqkv_kern<<<12288, 256, 0, stream>>>(Wq, Wk, Wv, bq, bk, bv, wtqkv, biasq);
    prep_wo_kern<<<4096, 256, 0, stream>>>(Wo, wot);
    gemm_bt<0><<<dim3(24, 32), 256, 0, stream>>>(xb, wtqkv, biasq, qb, kb, vtb, nullptr);
    attn_kern<<<dim3(8, 32), 256, 0, stream>>>(qb, kb, vtb, ob);
    gemm_bt<1><<<dim3(8, 32), 256, 0, stream>>>(ob, wot, bo, nullptr, nullptr, nullptr, out);
}

// Round 6
// 151.448 us; speedup vs baseline: 1.3850x; 1.0525x over previous
//
#include <hip/hip_runtime.h>

// B=2, S=2048, E=1024, H=16, D=64.  M = B*S = 4096.
// prep -> GEMM1 (QKV) -> flash attention (KV-split x2, partials) -> merge -> GEMM3.

typedef __attribute__((ext_vector_type(8)))  __bf16 bf16x8;
typedef __attribute__((ext_vector_type(4)))  __bf16 bf16x4;
typedef __attribute__((ext_vector_type(2)))  __bf16 bf16x2;
typedef __attribute__((ext_vector_type(4)))  float  f32x4;
typedef __attribute__((ext_vector_type(16))) float  f32x16;

#define LOG2E 1.4426950408889634f
#define SM_SC (0.125f * LOG2E)   // softmax scale folded with log2(e)

static __device__ __forceinline__ void gl2lds16(const void* g, void* l) {
    __builtin_amdgcn_global_load_lds(
        (__attribute__((address_space(1))) void*)(void*)g,
        (__attribute__((address_space(3))) void*)l, 16, 0, 0);
}

// ---------------- prep kernels ----------------
__global__ void prep_x_kern(const float* __restrict__ x, __bf16* __restrict__ xb) {
    int i = (blockIdx.x * 256 + threadIdx.x) * 4;
    f32x4 v = *(const f32x4*)(x + i);
    bf16x4 o = { (__bf16)v[0], (__bf16)v[1], (__bf16)v[2], (__bf16)v[3] };
    *(bf16x4*)(xb + i) = o;
}

// wt[n][k] = W_p[h][k][d],  n = p*1024 + h*64 + d (p in {q,k,v}); bias[n] = b_p[h*64+d]
__global__ void prep_wqkv_kern(const float* __restrict__ Wq, const float* __restrict__ Wk,
                               const float* __restrict__ Wv, const float* __restrict__ bq,
                               const float* __restrict__ bk, const float* __restrict__ bv,
                               __bf16* __restrict__ wt, float* __restrict__ bias) {
    int idx = blockIdx.x * 256 + threadIdx.x;     // 0..3145727
    int n = idx >> 10, kk = idx & 1023;
    int p = n >> 10, rm = n & 1023;
    int h = rm >> 6, d = rm & 63;
    const float* W = (p == 0) ? Wq : (p == 1) ? Wk : Wv;
    wt[idx] = (__bf16)W[(h << 16) + (kk << 6) + d];
    if (idx < 3072) {
        int p2 = idx >> 10, rm2 = idx & 1023;
        const float* bb = (p2 == 0) ? bq : (p2 == 1) ? bk : bv;
        bias[idx] = bb[rm2];
    }
}

// wt[n][k] = W_o[k][n]
__global__ void prep_wo_kern(const float* __restrict__ Wo, __bf16* __restrict__ wt) {
    int idx = blockIdx.x * 256 + threadIdx.x;    // 0..1048575
    int n = idx >> 10, kk = idx & 1023;
    wt[idx] = (__bf16)Wo[(kk << 10) + n];
}

// ---------------- GEMM: C[M][N] = A[M][1024] * Bt[N][1024]^T (+bias) ----------------
template <int EPI>
__global__ void __launch_bounds__(256, 2)
gemm_bt(const __bf16* __restrict__ A, const __bf16* __restrict__ Bt,
        const float* __restrict__ bias,
        __bf16* __restrict__ outq, __bf16* __restrict__ outk, __bf16* __restrict__ outv,
        float* __restrict__ outf)
{
    __shared__ __align__(16) __bf16 As[128 * 64];
    __shared__ __align__(16) __bf16 Bs[128 * 64];
    const int tid = threadIdx.x;
    const int wid = tid >> 6, lane = tid & 63;
    const int r = lane & 15, g = lane >> 4;
    const int m0 = blockIdx.y << 7, n0 = blockIdx.x << 7;
    const int wr = wid >> 1, wc = wid & 1;
    f32x4 acc[4][4] = {};
    for (int k0 = 0; k0 < 1024; k0 += 64) {
        #pragma unroll
        for (int c = 0; c < 4; ++c) {
            int cq = (c * 4 + wid) * 64 + lane;   // 16B chunk index in [0,1024)
            int row = cq >> 3, ci = cq & 7;
            gl2lds16(A  + (((size_t)(m0 + row)) << 10) + k0 + ci * 8, As + (c * 4 + wid) * 512);
            gl2lds16(Bt + (((size_t)(n0 + row)) << 10) + k0 + ci * 8, Bs + (c * 4 + wid) * 512);
        }
        __syncthreads();
        bf16x8 af[2][4], bfr[2][4];
        #pragma unroll
        for (int kh = 0; kh < 2; ++kh)
            #pragma unroll
            for (int i = 0; i < 4; ++i) {
                af[kh][i]  = *(const bf16x8*)&As[(wr * 64 + i * 16 + r) * 64 + kh * 32 + g * 8];
                bfr[kh][i] = *(const bf16x8*)&Bs[(wc * 64 + i * 16 + r) * 64 + kh * 32 + g * 8];
            }
        #pragma unroll
        for (int kh = 0; kh < 2; ++kh)
            #pragma unroll
            for (int mi = 0; mi < 4; ++mi)
                #pragma unroll
                for (int ni = 0; ni < 4; ++ni)
                    acc[mi][ni] = __builtin_amdgcn_mfma_f32_16x16x32_bf16(
                        af[kh][mi], bfr[kh][ni], acc[mi][ni], 0, 0, 0);
        __syncthreads();
    }
    if (EPI == 0) {
        #pragma unroll
        for (int ni = 0; ni < 4; ++ni) {
            int n = n0 + wc * 64 + ni * 16 + r;
            float bv = bias[n];
            int p = n >> 10, rem = n & 1023, h = rem >> 6, d = rem & 63;
            #pragma unroll
            for (int mi = 0; mi < 4; ++mi) {
                int mb = m0 + wr * 64 + mi * 16 + g * 4;
                int b = mb >> 11, s = mb & 2047;
                f32x4 v = acc[mi][ni];
                if (p < 2) {
                    __bf16* dst = (p == 0) ? outq : outk;
                    size_t base = (((size_t)(b * 16 + h)) * 2048 + s) * 64 + d;
                    #pragma unroll
                    for (int j = 0; j < 4; ++j)
                        dst[base + (size_t)j * 64] = (__bf16)(v[j] + bv);
                } else {
                    bf16x4 pk = { (__bf16)(v[0] + bv), (__bf16)(v[1] + bv),
                                  (__bf16)(v[2] + bv), (__bf16)(v[3] + bv) };
                    *(bf16x4*)&outv[(((size_t)(b * 16 + h)) * 64 + d) * 2048 + s] = pk;
                }
            }
        }
    } else {
        #pragma unroll
        for (int ni = 0; ni < 4; ++ni) {
            int n = n0 + wc * 64 + ni * 16 + r;
            float bv = bias[n];
            #pragma unroll
            for (int mi = 0; mi < 4; ++mi) {
                int mb = m0 + wr * 64 + mi * 16 + g * 4;
                f32x4 v = acc[mi][ni];
                #pragma unroll
                for (int j = 0; j < 4; ++j)
                    outf[((size_t)(mb + j) << 10) + n] = v[j] + bv;
            }
        }
    }
}

// ---------------- flash attention (swapped 32x32x16, KV-split x2) ----------------
// grid (16, 32): bx&7 = pair index x, bx>>3 = KV half. Block handles Q-blocks
// {15-x, x} sequentially; for segment qblk j it processes KV tiles
// [kvh*(j+1), (kvh+1)*(j+1)) -> 17 tiles/block uniformly. 512 blocks x 4 waves.
// Each segment writes l-normalized partial O (bf16) + (m,l) f32; merge_kern combines.
__global__ void __launch_bounds__(256)
attn_kern(const __bf16* __restrict__ q, const __bf16* __restrict__ k,
          const __bf16* __restrict__ vT, __bf16* __restrict__ pO0,
          __bf16* __restrict__ pO1, float* __restrict__ ml)
{
    __shared__ __align__(16) __bf16 Ks [2][64][72];
    __shared__ __align__(16) __bf16 VsT[2][64][72];
    __shared__ __align__(16) __bf16 Ps [4][32][72];
    const int tid = threadIdx.x, w = tid >> 6, lane = tid & 63;
    const int r31 = lane & 31, hi = lane >> 5;
    const int x = blockIdx.x & 7, kvh = blockIdx.x >> 3;
    const int bh = blockIdx.y, b = bh >> 4, h = bh & 15;
    const __bf16* qh  = q  + ((size_t)bh << 17);  // [2048][64]
    const __bf16* khp = k  + ((size_t)bh << 17);
    const __bf16* vhp = vT + ((size_t)bh << 17);  // [64][2048]
    __bf16* pO = kvh ? pO1 : pO0;
    const int srow = tid >> 3, sci = tid & 7;     // staging: 2 rounds x 32 rows

    for (int seg = 0; seg < 2; ++seg) {
        const int xq = (seg == 0) ? (15 - x) : x; // qblk index j
        const int qb0 = xq << 7;
        const int wrow0 = qb0 + w * 32;
        const int mg = wrow0 + r31;               // this lane's q-row
        const int tbeg = kvh * (xq + 1), tend = tbeg + (xq + 1);

        bf16x8 qf[4];
        #pragma unroll
        for (int kk = 0; kk < 4; ++kk)
            qf[kk] = *(const bf16x8*)&qh[(size_t)mg * 64 + kk * 16 + hi * 8];

        f32x16 oacc[2] = {};
        float mrun = -3.0e38f, lrun = 0.f;

        // stage first tile of this range into buffer 0
        #pragma unroll
        for (int it = 0; it < 2; ++it) {
            int row = srow + it * 32;
            *(bf16x8*)&Ks [0][row][sci * 8] = *(const bf16x8*)&khp[(size_t)(tbeg * 64 + row) * 64 + sci * 8];
            *(bf16x8*)&VsT[0][row][sci * 8] = *(const bf16x8*)&vhp[(size_t)row * 2048 + tbeg * 64 + sci * 8];
        }
        __syncthreads();

        for (int t = tbeg; t < tend; ++t) {
            const int cur = (t - tbeg) & 1, nxt = cur ^ 1;
            const int n0 = t << 6;
            const bool pre = (t + 1 < tend);
            bf16x8 nk[2], nv[2];
            if (pre) {   // issue next tile's loads; consumed after compute
                int n1 = n0 + 64;
                #pragma unroll
                for (int it = 0; it < 2; ++it) {
                    int row = srow + it * 32;
                    nk[it] = *(const bf16x8*)&khp[(size_t)(n1 + row) * 64 + sci * 8];
                    nv[it] = *(const bf16x8*)&vhp[(size_t)row * 2048 + n1 + sci * 8];
                }
            }
            if (n0 <= wrow0 + 31) {               // wave-uniform activity guard
                // ---- QK^T (swapped): sacc = S^T fragments ----
                f32x16 sacc[2] = {};
                #pragma unroll
                for (int kk = 0; kk < 4; ++kk) {
                    bf16x8 kf0 = *(const bf16x8*)&Ks[cur][r31]     [kk * 16 + hi * 8];
                    bf16x8 kf1 = *(const bf16x8*)&Ks[cur][32 + r31][kk * 16 + hi * 8];
                    sacc[0] = __builtin_amdgcn_mfma_f32_32x32x16_bf16(kf0, qf[kk], sacc[0], 0, 0, 0);
                    sacc[1] = __builtin_amdgcn_mfma_f32_32x32x16_bf16(kf1, qf[kk], sacc[1], 0, 0, 0);
                }
                // ---- causal mask (diagonal-touching tiles only) ----
                if (n0 + 63 > wrow0) {
                    #pragma unroll
                    for (int nf = 0; nf < 2; ++nf)
                        #pragma unroll
                        for (int i = 0; i < 16; ++i) {
                            int n = n0 + nf * 32 + (i & 3) + 8 * (i >> 2) + 4 * hi;
                            if (n > mg) sacc[nf][i] = -3.0e38f;
                        }
                }
                // ---- row max: tree reduce + cross-half shuffle ----
                float mx[16];
                #pragma unroll
                for (int i = 0; i < 16; ++i) mx[i] = fmaxf(sacc[0][i], sacc[1][i]);
                #pragma unroll
                for (int s = 8; s > 0; s >>= 1)
                    #pragma unroll
                    for (int i = 0; i < 8; ++i)
                        if (i < s) mx[i] = fmaxf(mx[i], mx[i + s]);
                float pm = fmaxf(mx[0], __shfl_xor(mx[0], 32));
                // ---- defer-max: rescale only when max grew past threshold ----
                if (!__all((pm - mrun) * SM_SC <= 8.0f)) {
                    float mnew = fmaxf(mrun, pm);
                    float fac = exp2f((mrun - mnew) * SM_SC);
                    lrun *= fac;
                    #pragma unroll
                    for (int df = 0; df < 2; ++df)
                        #pragma unroll
                        for (int i = 0; i < 16; ++i) oacc[df][i] *= fac;
                    mrun = mnew;
                }
                // ---- P = exp2, sum via tree + cross-half shuffle ----
                #pragma unroll
                for (int nf = 0; nf < 2; ++nf)
                    #pragma unroll
                    for (int i = 0; i < 16; ++i)
                        sacc[nf][i] = exp2f((sacc[nf][i] - mrun) * SM_SC);
                float sm[16];
                #pragma unroll
                for (int i = 0; i < 16; ++i) sm[i] = sacc[0][i] + sacc[1][i];
                #pragma unroll
                for (int s = 8; s > 0; s >>= 1)
                    #pragma unroll
                    for (int i = 0; i < 8; ++i)
                        if (i < s) sm[i] += sm[i + s];
                lrun += sm[0] + __shfl_xor(sm[0], 32);
                // ---- pack P to bf16 pairs, write wave-private Ps[m][n] ----
                #pragma unroll
                for (int nf = 0; nf < 2; ++nf)
                    #pragma unroll
                    for (int qd = 0; qd < 8; ++qd) {
                        bf16x2 pr = { (__bf16)sacc[nf][2 * qd], (__bf16)sacc[nf][2 * qd + 1] };
                        int dw = nf * 16 + 4 * (qd >> 1) + 2 * hi + (qd & 1);
                        ((bf16x2*)&Ps[w][r31][0])[dw] = pr;
                    }
                // ---- PV (swapped): oacc += V^T x P^T ----
                #pragma unroll
                for (int kk2 = 0; kk2 < 4; ++kk2) {
                    bf16x8 pf  = *(const bf16x8*)&Ps[w][r31][kk2 * 16 + hi * 8];
                    bf16x8 af0 = *(const bf16x8*)&VsT[cur][r31]     [kk2 * 16 + hi * 8];
                    bf16x8 af1 = *(const bf16x8*)&VsT[cur][32 + r31][kk2 * 16 + hi * 8];
                    oacc[0] = __builtin_amdgcn_mfma_f32_32x32x16_bf16(af0, pf, oacc[0], 0, 0, 0);
                    oacc[1] = __builtin_amdgcn_mfma_f32_32x32x16_bf16(af1, pf, oacc[1], 0, 0, 0);
                }
            }
            if (pre) {   // write prefetched tile into the other buffer
                #pragma unroll
                for (int it = 0; it < 2; ++it) {
                    int row = srow + it * 32;
                    *(bf16x8*)&Ks [nxt][row][sci * 8] = nk[it];
                    *(bf16x8*)&VsT[nxt][row][sci * 8] = nv[it];
                }
            }
            __syncthreads();                      // single barrier per tile
        }
        // ---- epilogue: l-normalized partial O^T + (m,l) ----
        float inv = (lrun > 0.f) ? 1.0f / lrun : 0.f;
        #pragma unroll
        for (int df = 0; df < 2; ++df)
            #pragma unroll
            for (int td = 0; td < 8; ++td) {
                bf16x2 pr = { (__bf16)(oacc[df][2 * td] * inv),
                              (__bf16)(oacc[df][2 * td + 1] * inv) };
                int d = df * 32 + 8 * (td >> 1) + 4 * hi + 2 * (td & 1);
                *(bf16x2*)&pO[((size_t)(b * 2048 + mg) << 10) + h * 64 + d] = pr;
            }
        if (hi == 0) {
            size_t mi = (((size_t)kvh * 32 + bh) * 2048 + mg) * 2;
            ml[mi] = mrun;
            ml[mi + 1] = lrun;
        }
    }
}

// ---------------- merge: ob = w0*pO0 + w1*ob ----------------
__global__ void merge_kern(const __bf16* __restrict__ pO0, const float* __restrict__ ml,
                           __bf16* __restrict__ ob)
{
    int i = blockIdx.x * 256 + threadIdx.x;       // 1,048,576 threads, 8 elems each
    int m = i >> 7, rem = i & 127, h = rem >> 3, d8 = (rem & 7) * 8;
    int bh = (m >> 11) * 16 + h, sr = m & 2047;
    size_t i0 = ((size_t)bh * 2048 + sr) * 2;
    float m0 = ml[i0], l0 = ml[i0 + 1];
    float m1 = ml[131072 + i0], l1 = ml[131072 + i0 + 1];
    float mx = fmaxf(m0, m1);
    float c0 = exp2f((m0 - mx) * SM_SC) * l0;
    float c1 = exp2f((m1 - mx) * SM_SC) * l1;
    float inv = 1.0f / (c0 + c1);                 // l0 > 0 always
    float w0 = c0 * inv, w1 = c1 * inv;
    size_t off = (size_t)m * 1024 + h * 64 + d8;
    bf16x8 a = *(const bf16x8*)(pO0 + off);
    bf16x8 c = *(const bf16x8*)(ob + off);
    bf16x8 r;
    #pragma unroll
    for (int j = 0; j < 8; ++j) r[j] = (__bf16)(w0 * (float)a[j] + w1 * (float)c[j]);
    *(bf16x8*)(ob + off) = r;
}

// ---------------- launch ----------------
extern "C" void kernel_launch(void* const* d_in, const int* in_sizes, int n_in,
                              void* d_out, int out_size, void* d_ws, size_t ws_size,
                              hipStream_t stream) {
    const float* x  = (const float*)d_in[0];
    const float* Wq = (const float*)d_in[1];
    const float* bq = (const float*)d_in[2];
    const float* Wk = (const float*)d_in[3];
    const float* bk = (const float*)d_in[4];
    const float* Wv = (const float*)d_in[5];
    const float* bv = (const float*)d_in[6];
    const float* Wo = (const float*)d_in[7];
    const float* bo = (const float*)d_in[8];
    float* out = (float*)d_out;
    char* ws = (char*)d_ws;
    // workspace layout (bytes), total ~50 MB; xb/wtqkv regions reused after GEMM1
    __bf16* xb    = (__bf16*)(ws + 0);          //  8 MB  x bf16 [4096][1024]; later pO0
    __bf16* wtqkv = (__bf16*)(ws + 8388608);    //  6 MB  qkv weights^T; later ml (2 MB)
    __bf16* wot   = (__bf16*)(ws + 14680064);   //  2 MB  W_o^T [1024][1024]
    float*  biasq = (float*) (ws + 16777216);   // 12 KB  fused qkv bias
    __bf16* qb    = (__bf16*)(ws + 16793600);   //  8 MB  q [32][2048][64]
    __bf16* kb    = (__bf16*)(ws + 25182208);   //  8 MB  k [32][2048][64]
    __bf16* vtb   = (__bf16*)(ws + 33570816);   //  8 MB  v^T [32][64][2048]
    __bf16* ob    = (__bf16*)(ws + 41959424);   //  8 MB  attn out [4096][1024]
    __bf16* pO0   = xb;                         //  8 MB  partial O (KV half 0)
    float*  mlbuf = (float*)(ws + 8388608);     //  2 MB  (m,l) per [half][bh][row]

    prep_x_kern<<<4096, 256, 0, stream>>>(x, xb);
    prep_wqkv_kern<<<12288, 256, 0, stream>>>(Wq, Wk, Wv, bq, bk, bv, wtqkv, biasq);
    prep_wo_kern<<<4096, 256, 0, stream>>>(Wo, wot);
    gemm_bt<0><<<dim3(24, 32), 256, 0, stream>>>(xb, wtqkv, biasq, qb, kb, vtb, nullptr);
    attn_kern<<<dim3(16, 32), 256, 0, stream>>>(qb, kb, vtb, pO0, ob, mlbuf);
    merge_kern<<<4096, 256, 0, stream>>>(pO0, mlbuf, ob);
    gemm_bt<1><<<dim3(8, 32), 256, 0, stream>>>(ob, wot, bo, nullptr, nullptr, nullptr, out);
}

// Round 7
// 137.193 us; speedup vs baseline: 1.5289x; 1.1039x over previous
//
#include <hip/hip_runtime.h>

// B=2, S=2048, E=1024, H=16, D=64.  M = B*S = 4096.
// prep -> GEMM1 (QKV) -> flash attention (KV-split x2, partials) -> merge -> GEMM3.

typedef __attribute__((ext_vector_type(8)))  __bf16 bf16x8;
typedef __attribute__((ext_vector_type(4)))  __bf16 bf16x4;
typedef __attribute__((ext_vector_type(2)))  __bf16 bf16x2;
typedef __attribute__((ext_vector_type(4)))  float  f32x4;
typedef __attribute__((ext_vector_type(16))) float  f32x16;

#define LOG2E 1.4426950408889634f
#define SM_SC (0.125f * LOG2E)   // softmax scale folded with log2(e)

static __device__ __forceinline__ void gl2lds16(const void* g, void* l) {
    __builtin_amdgcn_global_load_lds(
        (__attribute__((address_space(1))) void*)(void*)g,
        (__attribute__((address_space(3))) void*)l, 16, 0, 0);
}

// ---------------- prep kernels ----------------
__global__ void prep_x_kern(const float* __restrict__ x, __bf16* __restrict__ xb) {
    int i = (blockIdx.x * 256 + threadIdx.x) * 4;
    f32x4 v = *(const f32x4*)(x + i);
    bf16x4 o = { (__bf16)v[0], (__bf16)v[1], (__bf16)v[2], (__bf16)v[3] };
    *(bf16x4*)(xb + i) = o;
}

// wt[n][k] = W_p[h][k][d] via LDS 64x64 transpose; coalesced both sides.
// grid 768: blk = ((p*16+h)*16)+kt
__global__ void __launch_bounds__(256)
prep_wqkv_kern(const float* __restrict__ Wq, const float* __restrict__ Wk,
               const float* __restrict__ Wv, const float* __restrict__ bq,
               const float* __restrict__ bk, const float* __restrict__ bv,
               __bf16* __restrict__ wt, float* __restrict__ bias) {
    __shared__ float T[64][65];
    const int t = threadIdx.x;
    const int blk = blockIdx.x;
    const int kt = blk & 15, ph = blk >> 4;
    const int h = ph & 15, p = ph >> 4;
    const float* W  = (p == 0) ? Wq : (p == 1) ? Wk : Wv;
    const float* bb = (p == 0) ? bq : (p == 1) ? bk : bv;
    #pragma unroll
    for (int i = 0; i < 4; ++i) {
        int flat = i * 1024 + t * 4;
        int kr = flat >> 6, d4 = flat & 63;
        f32x4 v = *(const f32x4*)(W + (h << 16) + ((kt * 64 + kr) << 6) + d4);
        T[kr][d4] = v[0]; T[kr][d4 + 1] = v[1]; T[kr][d4 + 2] = v[2]; T[kr][d4 + 3] = v[3];
    }
    __syncthreads();
    const int d = t >> 2, kq = (t & 3) << 4;
    bf16x8 o0, o1;
    #pragma unroll
    for (int j = 0; j < 8; ++j) o0[j] = (__bf16)T[kq + j][d];
    #pragma unroll
    for (int j = 0; j < 8; ++j) o1[j] = (__bf16)T[kq + 8 + j][d];
    __bf16* dst = wt + (((size_t)(p * 1024 + h * 64 + d)) << 10) + kt * 64 + kq;
    *(bf16x8*)dst = o0;
    *(bf16x8*)(dst + 8) = o1;
    if (kt == 0 && t < 64) bias[p * 1024 + h * 64 + t] = bb[h * 64 + t];
}

// wt[n][k] = W_o[k][n] via LDS 64x64 transpose. grid 256: blk = ktile*16 + nt
__global__ void __launch_bounds__(256)
prep_wo_kern(const float* __restrict__ Wo, __bf16* __restrict__ wt) {
    __shared__ float T[64][65];
    const int t = threadIdx.x;
    const int nt = blockIdx.x & 15, ktile = blockIdx.x >> 4;
    #pragma unroll
    for (int i = 0; i < 4; ++i) {
        int flat = i * 1024 + t * 4;
        int kr = flat >> 6, n4 = flat & 63;
        f32x4 v = *(const f32x4*)(Wo + ((size_t)(ktile * 64 + kr) << 10) + nt * 64 + n4);
        T[kr][n4] = v[0]; T[kr][n4 + 1] = v[1]; T[kr][n4 + 2] = v[2]; T[kr][n4 + 3] = v[3];
    }
    __syncthreads();
    const int n = t >> 2, kq = (t & 3) << 4;
    bf16x8 o0, o1;
    #pragma unroll
    for (int j = 0; j < 8; ++j) o0[j] = (__bf16)T[kq + j][n];
    #pragma unroll
    for (int j = 0; j < 8; ++j) o1[j] = (__bf16)T[kq + 8 + j][n];
    __bf16* dst = wt + (((size_t)(nt * 64 + n)) << 10) + ktile * 64 + kq;
    *(bf16x8*)dst = o0;
    *(bf16x8*)(dst + 8) = o1;
}

// ---------------- GEMM: C[M][N] = A[M][1024] * Bt[N][1024]^T (+bias) ----------------
template <int EPI>
__global__ void __launch_bounds__(256, 2)
gemm_bt(const __bf16* __restrict__ A, const __bf16* __restrict__ Bt,
        const float* __restrict__ bias,
        __bf16* __restrict__ outq, __bf16* __restrict__ outk, __bf16* __restrict__ outv,
        float* __restrict__ outf)
{
    __shared__ __align__(16) __bf16 As[128 * 64];
    __shared__ __align__(16) __bf16 Bs[128 * 64];
    const int tid = threadIdx.x;
    const int wid = tid >> 6, lane = tid & 63;
    const int r = lane & 15, g = lane >> 4;
    const int m0 = blockIdx.y << 7, n0 = blockIdx.x << 7;
    const int wr = wid >> 1, wc = wid & 1;
    f32x4 acc[4][4] = {};
    for (int k0 = 0; k0 < 1024; k0 += 64) {
        #pragma unroll
        for (int c = 0; c < 4; ++c) {
            int cq = (c * 4 + wid) * 64 + lane;   // 16B chunk index in [0,1024)
            int row = cq >> 3, ci = cq & 7;
            gl2lds16(A  + (((size_t)(m0 + row)) << 10) + k0 + ci * 8, As + (c * 4 + wid) * 512);
            gl2lds16(Bt + (((size_t)(n0 + row)) << 10) + k0 + ci * 8, Bs + (c * 4 + wid) * 512);
        }
        __syncthreads();
        bf16x8 af[2][4], bfr[2][4];
        #pragma unroll
        for (int kh = 0; kh < 2; ++kh)
            #pragma unroll
            for (int i = 0; i < 4; ++i) {
                af[kh][i]  = *(const bf16x8*)&As[(wr * 64 + i * 16 + r) * 64 + kh * 32 + g * 8];
                bfr[kh][i] = *(const bf16x8*)&Bs[(wc * 64 + i * 16 + r) * 64 + kh * 32 + g * 8];
            }
        #pragma unroll
        for (int kh = 0; kh < 2; ++kh)
            #pragma unroll
            for (int mi = 0; mi < 4; ++mi)
                #pragma unroll
                for (int ni = 0; ni < 4; ++ni)
                    acc[mi][ni] = __builtin_amdgcn_mfma_f32_16x16x32_bf16(
                        af[kh][mi], bfr[kh][ni], acc[mi][ni], 0, 0, 0);
        __syncthreads();
    }
    if (EPI == 0) {
        #pragma unroll
        for (int ni = 0; ni < 4; ++ni) {
            int n = n0 + wc * 64 + ni * 16 + r;
            float bv = bias[n];
            int p = n >> 10, rem = n & 1023, h = rem >> 6, d = rem & 63;
            #pragma unroll
            for (int mi = 0; mi < 4; ++mi) {
                int mb = m0 + wr * 64 + mi * 16 + g * 4;
                int b = mb >> 11, s = mb & 2047;
                f32x4 v = acc[mi][ni];
                if (p < 2) {
                    __bf16* dst = (p == 0) ? outq : outk;
                    size_t base = (((size_t)(b * 16 + h)) * 2048 + s) * 64 + d;
                    #pragma unroll
                    for (int j = 0; j < 4; ++j)
                        dst[base + (size_t)j * 64] = (__bf16)(v[j] + bv);
                } else {
                    bf16x4 pk = { (__bf16)(v[0] + bv), (__bf16)(v[1] + bv),
                                  (__bf16)(v[2] + bv), (__bf16)(v[3] + bv) };
                    *(bf16x4*)&outv[(((size_t)(b * 16 + h)) * 64 + d) * 2048 + s] = pk;
                }
            }
        }
    } else {
        #pragma unroll
        for (int ni = 0; ni < 4; ++ni) {
            int n = n0 + wc * 64 + ni * 16 + r;
            float bv = bias[n];
            #pragma unroll
            for (int mi = 0; mi < 4; ++mi) {
                int mb = m0 + wr * 64 + mi * 16 + g * 4;
                f32x4 v = acc[mi][ni];
                #pragma unroll
                for (int j = 0; j < 4; ++j)
                    outf[((size_t)(mb + j) << 10) + n] = v[j] + bv;
            }
        }
    }
}

// ---------------- flash attention (swapped 32x32x16, KV-split x2) ----------------
// grid (16, 32): bx&7 = pair index x, bx>>3 = KV half. l-sum accumulated via MFMA
// (ones x P^T) -> no add-tree/shuffle; row-max check via __all on half-maxes ->
// cross-half shuffle only in the rare rescale branch (defer-max, THR=2^8).
__global__ void __launch_bounds__(256)
attn_kern(const __bf16* __restrict__ q, const __bf16* __restrict__ k,
          const __bf16* __restrict__ vT, __bf16* __restrict__ pO0,
          __bf16* __restrict__ pO1, float* __restrict__ ml)
{
    __shared__ __align__(16) __bf16 Ks [2][64][72];
    __shared__ __align__(16) __bf16 VsT[2][64][72];
    __shared__ __align__(16) __bf16 Ps [4][32][72];
    const int tid = threadIdx.x, w = tid >> 6, lane = tid & 63;
    const int r31 = lane & 31, hi = lane >> 5;
    const int x = blockIdx.x & 7, kvh = blockIdx.x >> 3;
    const int bh = blockIdx.y, b = bh >> 4, h = bh & 15;
    const __bf16* qh  = q  + ((size_t)bh << 17);  // [2048][64]
    const __bf16* khp = k  + ((size_t)bh << 17);
    const __bf16* vhp = vT + ((size_t)bh << 17);  // [64][2048]
    __bf16* pO = kvh ? pO1 : pO0;
    const int srow = tid >> 3, sci = tid & 7;     // staging: 2 rounds x 32 rows

    bf16x8 onesf;
    #pragma unroll
    for (int j = 0; j < 8; ++j) onesf[j] = (__bf16)1.0f;

    for (int seg = 0; seg < 2; ++seg) {
        const int xq = (seg == 0) ? (15 - x) : x; // qblk index j
        const int qb0 = xq << 7;
        const int wrow0 = qb0 + w * 32;
        const int mg = wrow0 + r31;               // this lane's q-row
        const int tbeg = kvh * (xq + 1), tend = tbeg + (xq + 1);

        bf16x8 qf[4];
        #pragma unroll
        for (int kk = 0; kk < 4; ++kk)
            qf[kk] = *(const bf16x8*)&qh[(size_t)mg * 64 + kk * 16 + hi * 8];

        f32x16 oacc[2] = {};
        f32x16 lacc = {};                          // l-sum accumulator (reg0 authoritative)
        float mrun = -3.0e38f;

        // stage first tile of this range into buffer 0
        #pragma unroll
        for (int it = 0; it < 2; ++it) {
            int row = srow + it * 32;
            *(bf16x8*)&Ks [0][row][sci * 8] = *(const bf16x8*)&khp[(size_t)(tbeg * 64 + row) * 64 + sci * 8];
            *(bf16x8*)&VsT[0][row][sci * 8] = *(const bf16x8*)&vhp[(size_t)row * 2048 + tbeg * 64 + sci * 8];
        }
        __syncthreads();

        for (int t = tbeg; t < tend; ++t) {
            const int cur = (t - tbeg) & 1, nxt = cur ^ 1;
            const int n0 = t << 6;
            const bool pre = (t + 1 < tend);
            bf16x8 nk[2], nv[2];
            if (pre) {   // issue next tile's loads; consumed after compute
                int n1 = n0 + 64;
                #pragma unroll
                for (int it = 0; it < 2; ++it) {
                    int row = srow + it * 32;
                    nk[it] = *(const bf16x8*)&khp[(size_t)(n1 + row) * 64 + sci * 8];
                    nv[it] = *(const bf16x8*)&vhp[(size_t)row * 2048 + n1 + sci * 8];
                }
            }
            if (n0 <= wrow0 + 31) {               // wave-uniform activity guard
                // ---- QK^T (swapped): sacc = S^T fragments ----
                f32x16 sacc[2] = {};
                #pragma unroll
                for (int kk = 0; kk < 4; ++kk) {
                    bf16x8 kf0 = *(const bf16x8*)&Ks[cur][r31]     [kk * 16 + hi * 8];
                    bf16x8 kf1 = *(const bf16x8*)&Ks[cur][32 + r31][kk * 16 + hi * 8];
                    sacc[0] = __builtin_amdgcn_mfma_f32_32x32x16_bf16(kf0, qf[kk], sacc[0], 0, 0, 0);
                    sacc[1] = __builtin_amdgcn_mfma_f32_32x32x16_bf16(kf1, qf[kk], sacc[1], 0, 0, 0);
                }
                // ---- causal mask (diagonal-touching tiles only) ----
                if (n0 + 63 > wrow0) {
                    #pragma unroll
                    for (int nf = 0; nf < 2; ++nf)
                        #pragma unroll
                        for (int i = 0; i < 16; ++i) {
                            int n = n0 + nf * 32 + (i & 3) + 8 * (i >> 2) + 4 * hi;
                            if (n > mg) sacc[nf][i] = -3.0e38f;
                        }
                }
                // ---- half-row max: tree reduce (no cross-half shuffle needed) ----
                float mx[16];
                #pragma unroll
                for (int i = 0; i < 16; ++i) mx[i] = fmaxf(sacc[0][i], sacc[1][i]);
                #pragma unroll
                for (int s = 8; s > 0; s >>= 1)
                    #pragma unroll
                    for (int i = 0; i < 8; ++i)
                        if (i < s) mx[i] = fmaxf(mx[i], mx[i + s]);
                float pmh = mx[0];
                // __all over 64 lanes covers both halves of every row -> exact check
                if (!__all((pmh - mrun) * SM_SC <= 8.0f)) {
                    float pm = fmaxf(pmh, __shfl_xor(pmh, 32));
                    float mnew = fmaxf(mrun, pm);
                    float fac = exp2f((mrun - mnew) * SM_SC);
                    lacc[0] *= fac;               // only reg0 is ever read
                    #pragma unroll
                    for (int df = 0; df < 2; ++df)
                        #pragma unroll
                        for (int i = 0; i < 16; ++i) oacc[df][i] *= fac;
                    mrun = mnew;
                }
                // ---- P = exp2 ----
                #pragma unroll
                for (int nf = 0; nf < 2; ++nf)
                    #pragma unroll
                    for (int i = 0; i < 16; ++i)
                        sacc[nf][i] = exp2f((sacc[nf][i] - mrun) * SM_SC);
                // ---- pack P to bf16 pairs, write wave-private Ps[m][n] ----
                #pragma unroll
                for (int nf = 0; nf < 2; ++nf)
                    #pragma unroll
                    for (int qd = 0; qd < 8; ++qd) {
                        bf16x2 pr = { (__bf16)sacc[nf][2 * qd], (__bf16)sacc[nf][2 * qd + 1] };
                        int dw = nf * 16 + 4 * (qd >> 1) + 2 * hi + (qd & 1);
                        ((bf16x2*)&Ps[w][r31][0])[dw] = pr;
                    }
                // ---- PV (swapped) + l-sum via MFMA (ones x P^T) ----
                #pragma unroll
                for (int kk2 = 0; kk2 < 4; ++kk2) {
                    bf16x8 pf  = *(const bf16x8*)&Ps[w][r31][kk2 * 16 + hi * 8];
                    bf16x8 af0 = *(const bf16x8*)&VsT[cur][r31]     [kk2 * 16 + hi * 8];
                    bf16x8 af1 = *(const bf16x8*)&VsT[cur][32 + r31][kk2 * 16 + hi * 8];
                    oacc[0] = __builtin_amdgcn_mfma_f32_32x32x16_bf16(af0, pf, oacc[0], 0, 0, 0);
                    oacc[1] = __builtin_amdgcn_mfma_f32_32x32x16_bf16(af1, pf, oacc[1], 0, 0, 0);
                    lacc    = __builtin_amdgcn_mfma_f32_32x32x16_bf16(onesf, pf, lacc, 0, 0, 0);
                }
            }
            if (pre) {   // write prefetched tile into the other buffer
                #pragma unroll
                for (int it = 0; it < 2; ++it) {
                    int row = srow + it * 32;
                    *(bf16x8*)&Ks [nxt][row][sci * 8] = nk[it];
                    *(bf16x8*)&VsT[nxt][row][sci * 8] = nv[it];
                }
            }
            __syncthreads();                      // single barrier per tile
        }
        // ---- epilogue: l-normalized partial O^T + (m,l) ----
        float lrun = lacc[0];
        float inv = (lrun > 0.f) ? 1.0f / lrun : 0.f;
        #pragma unroll
        for (int df = 0; df < 2; ++df)
            #pragma unroll
            for (int td = 0; td < 8; ++td) {
                bf16x2 pr = { (__bf16)(oacc[df][2 * td] * inv),
                              (__bf16)(oacc[df][2 * td + 1] * inv) };
                int d = df * 32 + 8 * (td >> 1) + 4 * hi + 2 * (td & 1);
                *(bf16x2*)&pO[((size_t)(b * 2048 + mg) << 10) + h * 64 + d] = pr;
            }
        if (hi == 0) {
            size_t mi = (((size_t)kvh * 32 + bh) * 2048 + mg) * 2;
            ml[mi] = mrun;
            ml[mi + 1] = lrun;
        }
    }
}

// ---------------- merge: ob = w0*pO0 + w1*ob ----------------
__global__ void merge_kern(const __bf16* __restrict__ pO0, const float* __restrict__ ml,
                           __bf16* __restrict__ ob)
{
    int i = blockIdx.x * 256 + threadIdx.x;       // 1,048,576 threads, 8 elems each
    int m = i >> 7, rem = i & 127, h = rem >> 3, d8 = (rem & 7) * 8;
    int bh = (m >> 11) * 16 + h, sr = m & 2047;
    size_t i0 = ((size_t)bh * 2048 + sr) * 2;
    float m0 = ml[i0], l0 = ml[i0 + 1];
    float m1 = ml[131072 + i0], l1 = ml[131072 + i0 + 1];
    float mx = fmaxf(m0, m1);
    float c0 = exp2f((m0 - mx) * SM_SC) * l0;
    float c1 = exp2f((m1 - mx) * SM_SC) * l1;
    float inv = 1.0f / (c0 + c1);                 // l0 > 0 always
    float w0 = c0 * inv, w1 = c1 * inv;
    size_t off = (size_t)m * 1024 + h * 64 + d8;
    bf16x8 a = *(const bf16x8*)(pO0 + off);
    bf16x8 c = *(const bf16x8*)(ob + off);
    bf16x8 r;
    #pragma unroll
    for (int j = 0; j < 8; ++j) r[j] = (__bf16)(w0 * (float)a[j] + w1 * (float)c[j]);
    *(bf16x8*)(ob + off) = r;
}

// ---------------- launch ----------------
extern "C" void kernel_launch(void* const* d_in, const int* in_sizes, int n_in,
                              void* d_out, int out_size, void* d_ws, size_t ws_size,
                              hipStream_t stream) {
    const float* x  = (const float*)d_in[0];
    const float* Wq = (const float*)d_in[1];
    const float* bq = (const float*)d_in[2];
    const float* Wk = (const float*)d_in[3];
    const float* bk = (const float*)d_in[4];
    const float* Wv = (const float*)d_in[5];
    const float* bv = (const float*)d_in[6];
    const float* Wo = (const float*)d_in[7];
    const float* bo = (const float*)d_in[8];
    float* out = (float*)d_out;
    char* ws = (char*)d_ws;
    // workspace layout (bytes), total ~50 MB; xb/wtqkv regions reused after GEMM1
    __bf16* xb    = (__bf16*)(ws + 0);          //  8 MB  x bf16 [4096][1024]; later pO0
    __bf16* wtqkv = (__bf16*)(ws + 8388608);    //  6 MB  qkv weights^T; later ml (2 MB)
    __bf16* wot   = (__bf16*)(ws + 14680064);   //  2 MB  W_o^T [1024][1024]
    float*  biasq = (float*) (ws + 16777216);   // 12 KB  fused qkv bias
    __bf16* qb    = (__bf16*)(ws + 16793600);   //  8 MB  q [32][2048][64]
    __bf16* kb    = (__bf16*)(ws + 25182208);   //  8 MB  k [32][2048][64]
    __bf16* vtb   = (__bf16*)(ws + 33570816);   //  8 MB  v^T [32][64][2048]
    __bf16* ob    = (__bf16*)(ws + 41959424);   //  8 MB  attn out [4096][1024]
    __bf16* pO0   = xb;                         //  8 MB  partial O (KV half 0)
    float*  mlbuf = (float*)(ws + 8388608);     //  2 MB  (m,l) per [half][bh][row]

    prep_x_kern<<<4096, 256, 0, stream>>>(x, xb);
    prep_wqkv_kern<<<768, 256, 0, stream>>>(Wq, Wk, Wv, bq, bk, bv, wtqkv, biasq);
    prep_wo_kern<<<256, 256, 0, stream>>>(Wo, wot);
    gemm_bt<0><<<dim3(24, 32), 256, 0, stream>>>(xb, wtqkv, biasq, qb, kb, vtb, nullptr);
    attn_kern<<<dim3(16, 32), 256, 0, stream>>>(qb, kb, vtb, pO0, ob, mlbuf);
    merge_kern<<<4096, 256, 0, stream>>>(pO0, mlbuf, ob);
    gemm_bt<1><<<dim3(8, 32), 256, 0, stream>>>(ob, wot, bo, nullptr, nullptr, nullptr, out);
}